// Round 1
// baseline (931.421 us; speedup 1.0000x reference)
//
#include <hip/hip_runtime.h>

// GraphSAGEConv fused kernel for MI355X (gfx950).
//
// Math restructure (exact up to fp32 reassociation):
//   h_neigh = mean_s nf[src] + (mean_s ef) @ W_edge + b_edge
//   out     = relu( nf @ Wl1 + nfagg @ Wl2 + efagg @ (W_edge @ Wl2)
//                   + (b_edge @ Wl2 + b_lin) )
// => one [N,320] @ [320,128] GEMM with Wcat = [Wl1; Wl2; W_edge@Wl2] (320x128)
//    and bias b_comb = b_edge@Wl2 + b_lin, both precomputed in prep_weights.
// This cuts the edge-transform GEMM 16x (E rows -> N rows): 33 GF -> 8.2 GF.

#define NODES    100000
#define NSAMP    16
#define NODE_DIM 128
#define EDGE_DIM 64
#define EMB_DIM  128
#define KTOT     320            // 128 self + 128 nfagg + 64 efagg
#define BN       64             // nodes per block
#define THREADS  512            // 8 waves
#define AGG_STRIDE 324          // 320 + 4 pad: b128 start bank = (4*lane+k)%32, conflict-free

// ---------------------------------------------------------------------------
// Tiny prep kernel: build Wcat[320][128] and b_comb[128] in workspace.
//   rows 0..255   : copy of W_lin (Wl1 rows 0..127 for self, Wl2 128..255 for nfagg)
//   rows 256..319 : W_comb = W_edge @ Wl2   (64x128, K=128)
//   block 320     : b_comb = b_lin + b_edge @ Wl2
// ---------------------------------------------------------------------------
__global__ __launch_bounds__(128) void prep_weights(
    const float* __restrict__ W_edge, const float* __restrict__ b_edge,
    const float* __restrict__ W_lin,  const float* __restrict__ b_lin,
    float* __restrict__ Wcat, float* __restrict__ b_comb)
{
    const int r = blockIdx.x;
    const int j = threadIdx.x;
    if (r < 256) {
        Wcat[r * 128 + j] = W_lin[r * 128 + j];
    } else if (r < 320) {
        const int e = r - 256;
        float s = 0.f;
        #pragma unroll 4
        for (int k = 0; k < 128; ++k)
            s = fmaf(W_edge[e * 128 + k], W_lin[(128 + k) * 128 + j], s);
        Wcat[r * 128 + j] = s;
    } else {
        float s = b_lin[j];
        #pragma unroll 4
        for (int k = 0; k < 128; ++k)
            s = fmaf(b_edge[k], W_lin[(128 + k) * 128 + j], s);
        b_comb[j] = s;
    }
}

// ---------------------------------------------------------------------------
// Fused kernel: per block of 64 nodes,
//   phase 1: stage [self | mean gathered nf | mean ef] into LDS agg[64][320]
//   phase 2: skinny GEMM agg @ Wcat, lane = node, W streamed via scalar loads
// ---------------------------------------------------------------------------
__global__ __launch_bounds__(THREADS) void sage_fused(
    const float* __restrict__ node_feat,
    const float* __restrict__ edge_feat,
    const int*   __restrict__ src_idx,
    const float* __restrict__ Wcat,
    const float* __restrict__ b_comb,
    float* __restrict__ out)
{
    __shared__ float agg[BN][AGG_STRIDE];
    __shared__ int   sIdx[BN * NSAMP];

    const int t     = threadIdx.x;
    const int base  = blockIdx.x * BN;
    const int nvalid = min(BN, NODES - base);

    // ---- stage src indices (1024 ints, coalesced) ----
    for (int i = t; i < BN * NSAMP; i += THREADS) {
        const int n = i >> 4;
        sIdx[i] = (n < nvalid) ? src_idx[(size_t)base * NSAMP + i] : 0;
    }

    // ---- self features -> agg[:, 0:128]  (64 rows x 32 float4, coalesced) ----
    #pragma unroll
    for (int p = 0; p < 4; ++p) {
        const int item = t + p * THREADS;      // 0..2047
        const int n  = item >> 5;
        const int kq = item & 31;
        float4 v = make_float4(0.f, 0.f, 0.f, 0.f);
        if (n < nvalid)
            v = *reinterpret_cast<const float4*>(
                    node_feat + (size_t)(base + n) * NODE_DIM + kq * 4);
        *reinterpret_cast<float4*>(&agg[n][kq * 4]) = v;
    }

    __syncthreads();   // sIdx visible for gather

    // ---- edge mean -> agg[:, 256:320]  (contiguous edge rows, coalesced) ----
    #pragma unroll
    for (int p = 0; p < 2; ++p) {
        const int item = t + p * THREADS;      // 0..1023
        const int n  = item >> 4;
        const int eq = item & 15;
        float4 a = make_float4(0.f, 0.f, 0.f, 0.f);
        if (n < nvalid) {
            const float* ep = edge_feat
                + ((size_t)(base + n) * NSAMP) * EDGE_DIM + eq * 4;
            #pragma unroll
            for (int s = 0; s < NSAMP; ++s) {
                const float4 v = *reinterpret_cast<const float4*>(ep + s * EDGE_DIM);
                a.x += v.x; a.y += v.y; a.z += v.z; a.w += v.w;
            }
        }
        a.x *= 0.0625f; a.y *= 0.0625f; a.z *= 0.0625f; a.w *= 0.0625f;
        *reinterpret_cast<float4*>(&agg[n][256 + eq * 4]) = a;
    }

    // ---- gathered neighbor mean -> agg[:, 128:256]
    //      (per (n,s): 32 consecutive lanes read one full 512B row -> L2/L3 friendly)
    #pragma unroll
    for (int p = 0; p < 4; ++p) {
        const int item = t + p * THREADS;      // 0..2047
        const int n  = item >> 5;
        const int kq = item & 31;
        float4 a = make_float4(0.f, 0.f, 0.f, 0.f);
        if (n < nvalid) {
            const int* ip = &sIdx[n * NSAMP];
            #pragma unroll
            for (int s = 0; s < NSAMP; ++s) {
                const int r = ip[s];
                const float4 v = *reinterpret_cast<const float4*>(
                        node_feat + (size_t)r * NODE_DIM + kq * 4);
                a.x += v.x; a.y += v.y; a.z += v.z; a.w += v.w;
            }
        }
        a.x *= 0.0625f; a.y *= 0.0625f; a.z *= 0.0625f; a.w *= 0.0625f;
        *reinterpret_cast<float4*>(&agg[n][128 + kq * 4]) = a;
    }

    __syncthreads();   // agg complete

    // ---- skinny GEMM: out[node][c] = relu( sum_k agg[node][k] * Wcat[k][c] + b_comb[c] )
    //      lane = node (64 nodes/wave), wave w owns cols [16w, 16w+16).
    //      W operand is wave-uniform -> SGPR stream (1 SGPR src allowed per v_fma).
    const int lane = t & 63;
    const int w    = t >> 6;
    const int wcol = __builtin_amdgcn_readfirstlane(w * 16);
    const float* __restrict__ Wp = Wcat + wcol;
    const float* __restrict__ bp = b_comb + wcol;

    float acc[16];
    #pragma unroll
    for (int j = 0; j < 16; ++j) acc[j] = 0.f;

    for (int k = 0; k < KTOT; k += 4) {
        const float4 in4 = *reinterpret_cast<const float4*>(&agg[lane][k]);
        const float in_[4] = { in4.x, in4.y, in4.z, in4.w };
        #pragma unroll
        for (int kk = 0; kk < 4; ++kk) {
            const float* wr = Wp + (k + kk) * EMB_DIM;
            #pragma unroll
            for (int j = 0; j < 16; ++j)
                acc[j] = fmaf(in_[kk], wr[j], acc[j]);
        }
    }

    if (lane < nvalid) {
        float* op = out + (size_t)(base + lane) * EMB_DIM + wcol;
        #pragma unroll
        for (int jq = 0; jq < 4; ++jq) {
            float4 v;
            v.x = fmaxf(acc[jq * 4 + 0] + bp[jq * 4 + 0], 0.f);
            v.y = fmaxf(acc[jq * 4 + 1] + bp[jq * 4 + 1], 0.f);
            v.z = fmaxf(acc[jq * 4 + 2] + bp[jq * 4 + 2], 0.f);
            v.w = fmaxf(acc[jq * 4 + 3] + bp[jq * 4 + 3], 0.f);
            *reinterpret_cast<float4*>(op + jq * 4) = v;
        }
    }
}

// ---------------------------------------------------------------------------
extern "C" void kernel_launch(void* const* d_in, const int* in_sizes, int n_in,
                              void* d_out, int out_size, void* d_ws, size_t ws_size,
                              hipStream_t stream)
{
    const float* node_feat = (const float*)d_in[0];  // [N,128]
    const float* edge_feat = (const float*)d_in[1];  // [E,64]
    const int*   src_idx   = (const int*)  d_in[2];  // [E]
    const float* W_edge    = (const float*)d_in[3];  // [64,128]
    const float* b_edge    = (const float*)d_in[4];  // [128]
    const float* W_lin     = (const float*)d_in[5];  // [256,128]
    const float* b_lin     = (const float*)d_in[6];  // [128]
    float* out = (float*)d_out;                      // [N,128]

    float* Wcat   = (float*)d_ws;                    // 320*128 floats
    float* b_comb = Wcat + KTOT * EMB_DIM;           // 128 floats

    prep_weights<<<dim3(321), dim3(128), 0, stream>>>(
        W_edge, b_edge, W_lin, b_lin, Wcat, b_comb);

    const int nblocks = (NODES + BN - 1) / BN;       // 1563
    sage_fused<<<dim3(nblocks), dim3(THREADS), 0, stream>>>(
        node_feat, edge_feat, src_idx, Wcat, b_comb, out);
}

// Round 2
// 747.294 us; speedup vs baseline: 1.2464x; 1.2464x over previous
//
#include <hip/hip_runtime.h>

// GraphSAGEConv fused kernel for MI355X (gfx950).
//
// Math restructure (exact up to fp32 reassociation):
//   h_neigh = mean_s nf[src] + (mean_s ef) @ W_edge + b_edge
//   out     = relu( nf @ Wl1 + nfagg @ Wl2 + efagg @ (W_edge @ Wl2)
//                   + (b_edge @ Wl2 + b_lin) )
// => one [N,320] @ [320,128] GEMM with Wcat (320x128) and bias b_comb,
//    both precomputed in prep_weights. Edge GEMM shrinks 16x (E->N rows).
//
// R2 change (occupancy fix): K is split into two 160-wide chunks staged
// into a single LDS buffer buf[64][164] (42 KB) with a persistent acc[16]
// across the two GEMM passes. LDS 87 KB -> 46 KB; __launch_bounds__(512,6)
// caps VGPRs so 3 blocks/CU can be resident (24 waves/CU vs 8 before).
// K-space is PERMUTED into chunk order; Wcat rows are permuted to match:
//   chunk0 rows: [ self 0..127        | efagg cols 0..31  ]
//   chunk1 rows: [ nfagg (gather) 0..127 | efagg cols 32..63 ]
// Wcat rows: [ Wl1(128) | Wcomb[0:32] | Wl2(128) | Wcomb[32:64] ]

#define NODES    100000
#define NSAMP    16
#define NODE_DIM 128
#define EDGE_DIM 64
#define EMB_DIM  128
#define KTOT     320
#define BN       64             // nodes per block
#define THREADS  512            // 8 waves
#define CH       160            // K-chunk size
#define CH_STRIDE 164           // +4 pad: b128 start bank = (4*lane+k)%32 -> 8/bank, minimal

// ---------------------------------------------------------------------------
// Prep kernel: build permuted Wcat[320][128] and b_comb[128] in workspace.
// ---------------------------------------------------------------------------
__global__ __launch_bounds__(128) void prep_weights(
    const float* __restrict__ W_edge, const float* __restrict__ b_edge,
    const float* __restrict__ W_lin,  const float* __restrict__ b_lin,
    float* __restrict__ Wcat, float* __restrict__ b_comb)
{
    const int r = blockIdx.x;
    const int j = threadIdx.x;
    if (r < 128) {
        // chunk0 self rows: Wl1
        Wcat[r * 128 + j] = W_lin[r * 128 + j];
    } else if (r < 160 || (r >= 288 && r < 320)) {
        // Wcomb = W_edge @ Wl2 ; rows 128..159 -> e 0..31, rows 288..319 -> e 32..63
        const int e = (r < 160) ? (r - 128) : (r - 256);
        float s = 0.f;
        #pragma unroll 4
        for (int k = 0; k < 128; ++k)
            s = fmaf(W_edge[e * 128 + k], W_lin[(128 + k) * 128 + j], s);
        Wcat[r * 128 + j] = s;
    } else if (r < 288) {
        // chunk1 nfagg rows: Wl2  (row 160+i <- W_lin[128+i])
        Wcat[r * 128 + j] = W_lin[(r - 32) * 128 + j];
    } else { // r == 320
        float s = b_lin[j];
        #pragma unroll 4
        for (int k = 0; k < 128; ++k)
            s = fmaf(b_edge[k], W_lin[(128 + k) * 128 + j], s);
        b_comb[j] = s;
    }
}

// ---------------------------------------------------------------------------
// Fused kernel, two-pass K-chunked.
// ---------------------------------------------------------------------------
__global__ __launch_bounds__(THREADS, 6) void sage_fused(
    const float* __restrict__ node_feat,
    const float* __restrict__ edge_feat,
    const int*   __restrict__ src_idx,
    const float* __restrict__ Wcat,
    const float* __restrict__ b_comb,
    float* __restrict__ out)
{
    __shared__ float buf[BN][CH_STRIDE];   // 42.0 KB
    __shared__ int   sIdx[BN * NSAMP];     //  4.0 KB

    const int t      = threadIdx.x;
    const int base   = blockIdx.x * BN;
    const int nvalid = min(BN, NODES - base);

    // ---- stage src indices (coalesced, used in chunk1) ----
    #pragma unroll
    for (int p = 0; p < 2; ++p) {
        const int i = t + p * THREADS;
        const int n = i >> 4;
        sIdx[i] = (n < nvalid) ? src_idx[(size_t)base * NSAMP + i] : 0;
    }

    // ---- chunk0: self features -> buf[:, 0:128] (coalesced float4) ----
    #pragma unroll
    for (int p = 0; p < 4; ++p) {
        const int item = t + p * THREADS;      // 0..2047
        const int n  = item >> 5;
        const int kq = item & 31;
        float4 v = make_float4(0.f, 0.f, 0.f, 0.f);
        if (n < nvalid)
            v = *reinterpret_cast<const float4*>(
                    node_feat + (size_t)(base + n) * NODE_DIM + kq * 4);
        *reinterpret_cast<float4*>(&buf[n][kq * 4]) = v;
    }

    // ---- chunk0: edge mean cols 0..31 -> buf[:, 128:160] ----
    {
        const int n = t >> 3;                  // 0..63
        const int q = t & 7;                   // 0..7 -> cols q*4..q*4+3
        float4 a = make_float4(0.f, 0.f, 0.f, 0.f);
        if (n < nvalid) {
            const float* ep = edge_feat
                + ((size_t)(base + n) * NSAMP) * EDGE_DIM + q * 4;
            #pragma unroll
            for (int s = 0; s < NSAMP; ++s) {
                const float4 v = *reinterpret_cast<const float4*>(ep + s * EDGE_DIM);
                a.x += v.x; a.y += v.y; a.z += v.z; a.w += v.w;
            }
        }
        a.x *= 0.0625f; a.y *= 0.0625f; a.z *= 0.0625f; a.w *= 0.0625f;
        *reinterpret_cast<float4*>(&buf[n][128 + q * 4]) = a;
    }

    __syncthreads();   // chunk0 + sIdx visible

    // ---- GEMM setup: lane = node, wave w owns cols [16w, 16w+16) ----
    const int lane = t & 63;
    const int w    = t >> 6;
    const int wcol = __builtin_amdgcn_readfirstlane(w * 16);
    const float* __restrict__ Wp0 = Wcat + wcol;                    // rows 0..159
    const float* __restrict__ Wp1 = Wcat + CH * EMB_DIM + wcol;     // rows 160..319
    const float* __restrict__ bp  = b_comb + wcol;

    float acc[16];
    #pragma unroll
    for (int j = 0; j < 16; ++j) acc[j] = 0.f;

    // ---- GEMM pass 0 (k = 0..159) ----
    for (int k = 0; k < CH; k += 4) {
        const float4 in4 = *reinterpret_cast<const float4*>(&buf[lane][k]);
        const float in_[4] = { in4.x, in4.y, in4.z, in4.w };
        #pragma unroll
        for (int kk = 0; kk < 4; ++kk) {
            const float* wr = Wp0 + (k + kk) * EMB_DIM;
            #pragma unroll
            for (int j = 0; j < 16; ++j)
                acc[j] = fmaf(in_[kk], wr[j], acc[j]);
        }
    }

    __syncthreads();   // pass-0 reads done, buf reusable

    // ---- chunk1: gathered neighbor mean -> buf[:, 0:128] ----
    #pragma unroll 2
    for (int p = 0; p < 4; ++p) {
        const int item = t + p * THREADS;      // 0..2047
        const int n  = item >> 5;
        const int kq = item & 31;
        float4 a = make_float4(0.f, 0.f, 0.f, 0.f);
        if (n < nvalid) {
            const int* ip = &sIdx[n * NSAMP];
            #pragma unroll
            for (int s = 0; s < NSAMP; ++s) {
                const int r = ip[s];
                const float4 v = *reinterpret_cast<const float4*>(
                        node_feat + (size_t)r * NODE_DIM + kq * 4);
                a.x += v.x; a.y += v.y; a.z += v.z; a.w += v.w;
            }
        }
        a.x *= 0.0625f; a.y *= 0.0625f; a.z *= 0.0625f; a.w *= 0.0625f;
        *reinterpret_cast<float4*>(&buf[n][kq * 4]) = a;
    }

    // ---- chunk1: edge mean cols 32..63 -> buf[:, 128:160] ----
    {
        const int n = t >> 3;
        const int q = t & 7;
        float4 a = make_float4(0.f, 0.f, 0.f, 0.f);
        if (n < nvalid) {
            const float* ep = edge_feat
                + ((size_t)(base + n) * NSAMP) * EDGE_DIM + 32 + q * 4;
            #pragma unroll
            for (int s = 0; s < NSAMP; ++s) {
                const float4 v = *reinterpret_cast<const float4*>(ep + s * EDGE_DIM);
                a.x += v.x; a.y += v.y; a.z += v.z; a.w += v.w;
            }
        }
        a.x *= 0.0625f; a.y *= 0.0625f; a.z *= 0.0625f; a.w *= 0.0625f;
        *reinterpret_cast<float4*>(&buf[n][128 + q * 4]) = a;
    }

    __syncthreads();   // chunk1 visible

    // ---- GEMM pass 1 (rows 160..319), accumulate into acc ----
    for (int k = 0; k < CH; k += 4) {
        const float4 in4 = *reinterpret_cast<const float4*>(&buf[lane][k]);
        const float in_[4] = { in4.x, in4.y, in4.z, in4.w };
        #pragma unroll
        for (int kk = 0; kk < 4; ++kk) {
            const float* wr = Wp1 + (k + kk) * EMB_DIM;
            #pragma unroll
            for (int j = 0; j < 16; ++j)
                acc[j] = fmaf(in_[kk], wr[j], acc[j]);
        }
    }

    // ---- epilogue: bias + relu + coalesced float4 store ----
    if (lane < nvalid) {
        float* op = out + (size_t)(base + lane) * EMB_DIM + wcol;
        #pragma unroll
        for (int jq = 0; jq < 4; ++jq) {
            float4 v;
            v.x = fmaxf(acc[jq * 4 + 0] + bp[jq * 4 + 0], 0.f);
            v.y = fmaxf(acc[jq * 4 + 1] + bp[jq * 4 + 1], 0.f);
            v.z = fmaxf(acc[jq * 4 + 2] + bp[jq * 4 + 2], 0.f);
            v.w = fmaxf(acc[jq * 4 + 3] + bp[jq * 4 + 3], 0.f);
            *reinterpret_cast<float4*>(op + jq * 4) = v;
        }
    }
}

// ---------------------------------------------------------------------------
extern "C" void kernel_launch(void* const* d_in, const int* in_sizes, int n_in,
                              void* d_out, int out_size, void* d_ws, size_t ws_size,
                              hipStream_t stream)
{
    const float* node_feat = (const float*)d_in[0];  // [N,128]
    const float* edge_feat = (const float*)d_in[1];  // [E,64]
    const int*   src_idx   = (const int*)  d_in[2];  // [E]
    const float* W_edge    = (const float*)d_in[3];  // [64,128]
    const float* b_edge    = (const float*)d_in[4];  // [128]
    const float* W_lin     = (const float*)d_in[5];  // [256,128]
    const float* b_lin     = (const float*)d_in[6];  // [128]
    float* out = (float*)d_out;                      // [N,128]

    float* Wcat   = (float*)d_ws;                    // 320*128 floats
    float* b_comb = Wcat + KTOT * EMB_DIM;           // 128 floats

    prep_weights<<<dim3(321), dim3(128), 0, stream>>>(
        W_edge, b_edge, W_lin, b_lin, Wcat, b_comb);

    const int nblocks = (NODES + BN - 1) / BN;       // 1563
    sage_fused<<<dim3(nblocks), dim3(THREADS), 0, stream>>>(
        node_feat, edge_feat, src_idx, Wcat, b_comb, out);
}

// Round 6
// 735.852 us; speedup vs baseline: 1.2658x; 1.0155x over previous
//
#include <hip/hip_runtime.h>

// GraphSAGEConv fused kernel for MI355X (gfx950).
//
// Math restructure (exact up to fp32 reassociation):
//   out = relu( nf @ Wl1 + (mean_s nf[src]) @ Wl2 + (mean_s ef) @ (W_edge @ Wl2)
//               + (b_edge @ Wl2 + b_lin) )
// => one [N,320] @ [320,128] GEMM with precomputed Wcat (320x128) + b_comb.
//
// R3 (resubmitted; broker timeouts R3/R4/R5): latency fix. 4 K-chunks
// {64,96,64,96} staged through one LDS buffer buf[64][100] (25.6 KB) + sIdx
// (4 KB) = 29.7 KB -> 4 blocks/CU at 32 waves (100% occupancy;
// launch_bounds(512,8) caps VGPR at 64). Edge means are computed into
// REGISTERS at kernel entry (full 256B rows read once, coalesced), issued
// before any barrier so the 410 MB edge stream overlaps chunk-0 staging +
// GEMM0; written to LDS in chunks 1 and 3.
// K-permutation (same as R2, prep_weights unchanged):
//   Wcat rows: [ Wl1(128) | Wcomb[0:32] | Wl2(128) | Wcomb[32:64] ]
//   chunk0 = rows   0..63   (self  cols   0..63)
//   chunk1 = rows  64..159  (self 64..127 | ef 0..31)
//   chunk2 = rows 160..223  (gather cols  0..63)
//   chunk3 = rows 224..319  (gather 64..127 | ef 32..63)

#define NODES    100000
#define NSAMP    16
#define NODE_DIM 128
#define EDGE_DIM 64
#define EMB_DIM  128
#define KTOT     320
#define BN       64
#define THREADS  512
#define BSTRIDE  100            // 96 max chunk + 4 pad; 100 % 8 == 4 -> uniform bank spread

// ---------------------------------------------------------------------------
__global__ __launch_bounds__(128) void prep_weights(
    const float* __restrict__ W_edge, const float* __restrict__ b_edge,
    const float* __restrict__ W_lin,  const float* __restrict__ b_lin,
    float* __restrict__ Wcat, float* __restrict__ b_comb)
{
    const int r = blockIdx.x;
    const int j = threadIdx.x;
    if (r < 128) {
        Wcat[r * 128 + j] = W_lin[r * 128 + j];                  // Wl1
    } else if (r < 160 || (r >= 288 && r < 320)) {
        const int e = (r < 160) ? (r - 128) : (r - 256);         // Wcomb = W_edge@Wl2
        float s = 0.f;
        #pragma unroll 4
        for (int k = 0; k < 128; ++k)
            s = fmaf(W_edge[e * 128 + k], W_lin[(128 + k) * 128 + j], s);
        Wcat[r * 128 + j] = s;
    } else if (r < 288) {
        Wcat[r * 128 + j] = W_lin[(r - 32) * 128 + j];           // Wl2
    } else {
        float s = b_lin[j];
        #pragma unroll 4
        for (int k = 0; k < 128; ++k)
            s = fmaf(b_edge[k], W_lin[(128 + k) * 128 + j], s);
        b_comb[j] = s;
    }
}

// ---------------------------------------------------------------------------
__global__ __launch_bounds__(THREADS, 8) void sage_fused(
    const float* __restrict__ node_feat,
    const float* __restrict__ edge_feat,
    const int*   __restrict__ src_idx,
    const float* __restrict__ Wcat,
    const float* __restrict__ b_comb,
    float* __restrict__ out)
{
    __shared__ float buf[BN][BSTRIDE];     // 25.6 KB
    __shared__ int   sIdx[BN * NSAMP];     //  4.0 KB

    const int t      = threadIdx.x;
    const int base   = blockIdx.x * BN;
    const int nvalid = min(BN, NODES - base);

    // ---- edge-mean prefetch into registers (dominant HBM stream, issued first)
    //      thread -> (node en, quad eq); full 256B rows, each read exactly once.
    const int en = t >> 3;                 // 0..63
    const int eq = t & 7;                  // 0..7
    float4 aLo = make_float4(0.f, 0.f, 0.f, 0.f);   // ef cols eq*4    .. +3
    float4 aHi = make_float4(0.f, 0.f, 0.f, 0.f);   // ef cols 32+eq*4 .. +3
    if (en < nvalid) {
        const float* ep = edge_feat + ((size_t)(base + en) * NSAMP) * EDGE_DIM;
        #pragma unroll
        for (int s = 0; s < NSAMP; ++s) {
            const float4 v0 = *reinterpret_cast<const float4*>(ep + s * EDGE_DIM + eq * 4);
            const float4 v1 = *reinterpret_cast<const float4*>(ep + s * EDGE_DIM + 32 + eq * 4);
            aLo.x += v0.x; aLo.y += v0.y; aLo.z += v0.z; aLo.w += v0.w;
            aHi.x += v1.x; aHi.y += v1.y; aHi.z += v1.z; aHi.w += v1.w;
        }
    }
    aLo.x *= 0.0625f; aLo.y *= 0.0625f; aLo.z *= 0.0625f; aLo.w *= 0.0625f;
    aHi.x *= 0.0625f; aHi.y *= 0.0625f; aHi.z *= 0.0625f; aHi.w *= 0.0625f;

    // ---- stage src indices ----
    #pragma unroll
    for (int p = 0; p < 2; ++p) {
        const int i = t + p * THREADS;
        const int n = i >> 4;
        sIdx[i] = (n < nvalid) ? src_idx[(size_t)base * NSAMP + i] : 0;
    }

    // ---- chunk0 stage: self cols 0..63 -> buf[:, 0:64] ----
    #pragma unroll
    for (int p = 0; p < 2; ++p) {
        const int item = t + p * THREADS;  // 0..1023
        const int n  = item >> 4;
        const int kq = item & 15;
        float4 v = make_float4(0.f, 0.f, 0.f, 0.f);
        if (n < nvalid)
            v = *reinterpret_cast<const float4*>(
                    node_feat + (size_t)(base + n) * NODE_DIM + kq * 4);
        *reinterpret_cast<float4*>(&buf[n][kq * 4]) = v;
    }

    __syncthreads();

    // ---- GEMM setup: lane = node, wave w -> cols [16w, 16w+16) (wave-uniform) ----
    const int lane = t & 63;
    const int w    = t >> 6;
    const int wcol = __builtin_amdgcn_readfirstlane(w * 16);
    const float* __restrict__ bp = b_comb + wcol;

    float acc[16];
    #pragma unroll
    for (int j = 0; j < 16; ++j) acc[j] = 0.f;

    // GEMM over one staged chunk: buf cols [0,W), Wcat rows [rowBase, rowBase+W)
#define GEMM_PASS(W_, rowBase_)                                                \
    {                                                                          \
        const float* __restrict__ Wp = Wcat + (rowBase_) * EMB_DIM + wcol;     \
        for (int k = 0; k < (W_); k += 4) {                                    \
            const float4 in4 = *reinterpret_cast<const float4*>(&buf[lane][k]);\
            const float in_[4] = { in4.x, in4.y, in4.z, in4.w };               \
            _Pragma("unroll")                                                  \
            for (int kk = 0; kk < 4; ++kk) {                                   \
                const float* wr = Wp + (k + kk) * EMB_DIM;                     \
                _Pragma("unroll")                                              \
                for (int j = 0; j < 16; ++j)                                   \
                    acc[j] = fmaf(in_[kk], wr[j], acc[j]);                     \
            }                                                                  \
        }                                                                      \
    }

    // ---- GEMM pass 0 ----
    GEMM_PASS(64, 0)
    __syncthreads();

    // ---- chunk1 stage: self cols 64..127 -> buf[:,0:64]; ef lo -> buf[:,64:96] ----
    #pragma unroll
    for (int p = 0; p < 2; ++p) {
        const int item = t + p * THREADS;
        const int n  = item >> 4;
        const int kq = item & 15;
        float4 v = make_float4(0.f, 0.f, 0.f, 0.f);
        if (n < nvalid)
            v = *reinterpret_cast<const float4*>(
                    node_feat + (size_t)(base + n) * NODE_DIM + 64 + kq * 4);
        *reinterpret_cast<float4*>(&buf[n][kq * 4]) = v;
    }
    *reinterpret_cast<float4*>(&buf[en][64 + eq * 4]) = aLo;

    __syncthreads();

    // ---- GEMM pass 1 ----
    GEMM_PASS(96, 64)
    __syncthreads();

    // ---- chunk2 stage: gather mean cols 0..63 -> buf[:,0:64] ----
    #pragma unroll
    for (int p = 0; p < 2; ++p) {
        const int item = t + p * THREADS;
        const int n  = item >> 4;
        const int kq = item & 15;
        float4 a = make_float4(0.f, 0.f, 0.f, 0.f);
        if (n < nvalid) {
            const int* ip = &sIdx[n * NSAMP];
            #pragma unroll
            for (int s = 0; s < NSAMP; ++s) {
                const int r = ip[s];
                const float4 v = *reinterpret_cast<const float4*>(
                        node_feat + (size_t)r * NODE_DIM + kq * 4);
                a.x += v.x; a.y += v.y; a.z += v.z; a.w += v.w;
            }
        }
        a.x *= 0.0625f; a.y *= 0.0625f; a.z *= 0.0625f; a.w *= 0.0625f;
        *reinterpret_cast<float4*>(&buf[n][kq * 4]) = a;
    }

    __syncthreads();

    // ---- GEMM pass 2 ----
    GEMM_PASS(64, 160)
    __syncthreads();

    // ---- chunk3 stage: gather mean cols 64..127 -> buf[:,0:64]; ef hi -> buf[:,64:96] ----
    #pragma unroll
    for (int p = 0; p < 2; ++p) {
        const int item = t + p * THREADS;
        const int n  = item >> 4;
        const int kq = item & 15;
        float4 a = make_float4(0.f, 0.f, 0.f, 0.f);
        if (n < nvalid) {
            const int* ip = &sIdx[n * NSAMP];
            #pragma unroll
            for (int s = 0; s < NSAMP; ++s) {
                const int r = ip[s];
                const float4 v = *reinterpret_cast<const float4*>(
                        node_feat + (size_t)r * NODE_DIM + 64 + kq * 4);
                a.x += v.x; a.y += v.y; a.z += v.z; a.w += v.w;
            }
        }
        a.x *= 0.0625f; a.y *= 0.0625f; a.z *= 0.0625f; a.w *= 0.0625f;
        *reinterpret_cast<float4*>(&buf[n][kq * 4]) = a;
    }
    *reinterpret_cast<float4*>(&buf[en][64 + eq * 4]) = aHi;

    __syncthreads();

    // ---- GEMM pass 3 ----
    GEMM_PASS(96, 224)

    // ---- epilogue: bias + relu + coalesced float4 store ----
    if (lane < nvalid) {
        float* op = out + (size_t)(base + lane) * EMB_DIM + wcol;
        #pragma unroll
        for (int jq = 0; jq < 4; ++jq) {
            float4 v;
            v.x = fmaxf(acc[jq * 4 + 0] + bp[jq * 4 + 0], 0.f);
            v.y = fmaxf(acc[jq * 4 + 1] + bp[jq * 4 + 1], 0.f);
            v.z = fmaxf(acc[jq * 4 + 2] + bp[jq * 4 + 2], 0.f);
            v.w = fmaxf(acc[jq * 4 + 3] + bp[jq * 4 + 3], 0.f);
            *reinterpret_cast<float4*>(op + jq * 4) = v;
        }
    }
#undef GEMM_PASS
}

// ---------------------------------------------------------------------------
extern "C" void kernel_launch(void* const* d_in, const int* in_sizes, int n_in,
                              void* d_out, int out_size, void* d_ws, size_t ws_size,
                              hipStream_t stream)
{
    const float* node_feat = (const float*)d_in[0];  // [N,128]
    const float* edge_feat = (const float*)d_in[1];  // [E,64]
    const int*   src_idx   = (const int*)  d_in[2];  // [E]
    const float* W_edge    = (const float*)d_in[3];  // [64,128]
    const float* b_edge    = (const float*)d_in[4];  // [128]
    const float* W_lin     = (const float*)d_in[5];  // [256,128]
    const float* b_lin     = (const float*)d_in[6];  // [128]
    float* out = (float*)d_out;                      // [N,128]

    float* Wcat   = (float*)d_ws;                    // 320*128 floats
    float* b_comb = Wcat + KTOT * EMB_DIM;           // 128 floats

    prep_weights<<<dim3(321), dim3(128), 0, stream>>>(
        W_edge, b_edge, W_lin, b_lin, Wcat, b_comb);

    const int nblocks = (NODES + BN - 1) / BN;       // 1563
    sage_fused<<<dim3(nblocks), dim3(THREADS), 0, stream>>>(
        node_feat, edge_feat, src_idx, Wcat, b_comb, out);
}